// Round 10
// baseline (63.225 us; speedup 1.0000x reference)
//
#include <hip/hip_runtime.h>

// 2-bit child->parent distance per column c (50-bit word): d = (DPACK >> 2c) & 3.
// d==0 -> not a child. Parent of column c is column c-d (d<=3, same row).
#define DPACK 0x00012493939124E4ULL
#define TILE 2048u      // floats per array per tile (8 KB)
#define NT 4            // tiles per block -> 8192 elements per block

__device__ __forceinline__ float parsel(unsigned d, float w1, float w2, float w3) {
    return (d == 1u) ? w1 : (d == 2u) ? w2 : w3;   // caller masks d==0
}

__global__ __launch_bounds__(256)
void hbfl_kernel(const float* __restrict__ logits,
                 const float* __restrict__ targets,
                 float* __restrict__ out,
                 unsigned n, float scale)
{
    // Double-buffered LDS tiles: 2*(8KB+8KB) = 32 KB -> 4 blocks/CU.
    __shared__ float bufL[2][TILE];
    __shared__ float bufT[2][TILE];
    __shared__ float wsum[4];

    const unsigned tid = threadIdx.x;
    const unsigned wv  = tid >> 6;                 // wave id (uniform per wave)
    const unsigned ln  = tid & 63u;
    const unsigned chunk = blockIdx.x * (NT * TILE);
    const unsigned nm4 = n - 4u;

    // DMA-stage one tile (both arrays) into buffer b. LDS dest is HW-linear
    // (wave-uniform base + lane*16); source addresses clamped for the tail
    // (duplicated data, masked at accumulate). No VGPR destinations -> the
    // register allocator cannot collapse the in-flight depth (R4/5/8/9).
    auto stage = [&](int b, unsigned tb) {
        #pragma unroll
        for (unsigned k = 0; k < 2; ++k) {
            const unsigned fo = k * 1024u + wv * 256u;   // wave-uniform
            unsigned ge = tb + fo + 4u * ln;             // per-lane source
            ge = (ge <= nm4) ? ge : nm4;
            __builtin_amdgcn_global_load_lds(
                (const __attribute__((address_space(1))) void*)(logits + ge),
                (__attribute__((address_space(3))) void*)&bufL[b][fo], 16, 0, 0);
            __builtin_amdgcn_global_load_lds(
                (const __attribute__((address_space(1))) void*)(targets + ge),
                (__attribute__((address_space(3))) void*)&bufT[b][fo], 16, 0, 0);
        }
    };

    // 16B of targets preceding the tile (for thread 0's parent window);
    // register-carried one phase ahead. All lanes same address -> 1 line.
    auto halo = [&](unsigned tb) -> float4 {
        const unsigned e = (tb >= 4u) ? tb - 4u : 0u;    // block0/tile0: never selected
        return *(const float4*)(targets + e);
    };

    auto comp = [&](const float* L, const float* T, unsigned tb, float4 hal) -> float {
        const unsigned o = 8u * tid;
        const float4 xa  = *(const float4*)(L + o);
        const float4 xb  = *(const float4*)(L + o + 4u);
        const float4 ta  = *(const float4*)(T + o);
        const float4 tb4 = *(const float4*)(T + o + 4u);
        float4 tp = *(const float4*)(T + (tid ? o - 4u : 0u));
        if (tid == 0u) tp = hal;

        // Column phase of this thread's 8 elements: rotate the 50-bit DPACK.
        const unsigned ge0 = tb + o;
        const unsigned sh  = 2u * (ge0 % 25u);
        const unsigned dd  = (unsigned)((DPACK >> sh) | (DPACK << (50u - sh)));

        // Targets window, flat elements ge0-4 .. ge0+7:  tp | ta | tb4
        const float xs[8] = {xa.x,xa.y,xa.z,xa.w, xb.x,xb.y,xb.z,xb.w};
        const float ts[8] = {ta.x,ta.y,ta.z,ta.w, tb4.x,tb4.y,tb4.z,tb4.w};
        const float tpar[8] = {
            parsel((dd >> 0) & 3u,  tp.w,  tp.z,  tp.y),
            parsel((dd >> 2) & 3u,  ta.x,  tp.w,  tp.z),
            parsel((dd >> 4) & 3u,  ta.y,  ta.x,  tp.w),
            parsel((dd >> 6) & 3u,  ta.z,  ta.y,  ta.x),
            parsel((dd >> 8) & 3u,  ta.w,  ta.z,  ta.y),
            parsel((dd >> 10) & 3u, tb4.x, ta.w,  ta.z),
            parsel((dd >> 12) & 3u, tb4.y, tb4.x, ta.w),
            parsel((dd >> 14) & 3u, tb4.z, tb4.y, tb4.x)};

        float a = 0.0f;
        #pragma unroll
        for (int j = 0; j < 8; ++j) {
            const float x = xs[j], t = ts[j];
            // Binary targets (t in {0,1}): e = exp(-x*(2t-1));
            // bce = ln(1+e); pt = 1/(1+e); 1-pt = e*pt.   (R5-verified)
            const float sgn = __builtin_fmaf(2.0f, t, -1.0f);
            const float e   = __expf(-x * sgn);
            const float den = 1.0f + e;
            const float pt  = __builtin_amdgcn_rcpf(den);
            const float bce = __logf(den);
            const float omp = e * pt;
            const float fo  = omp * omp * bce;                // focal / ALPHA
            float wgt = __builtin_fmaf(t, 0.375f, 0.1875f);   // ALPHA*classw
            const unsigned dj = (dd >> (2 * j)) & 3u;
            const bool dbl = (dj != 0u) & (x > 0.5f) & (tpar[j] < 0.5f);
            wgt = dbl ? wgt + wgt : wgt;                      // (1+penalty)
            wgt = (ge0 + (unsigned)j < n) ? wgt : 0.0f;       // tail mask
            a = __builtin_fmaf(fo, wgt, a);
        }
        return a;
    };

    float acc = 0.0f;

    // 2-phase pipeline (T3-minimum): stage(t+1) in flight while compute(t);
    // one vmcnt(0)+barrier (__syncthreads) per tile is the only drain.
    stage(0, chunk);
    float4 h0 = halo(chunk);
    __syncthreads();                                  // tile0 ready

    stage(1, chunk + TILE);
    float4 h1 = halo(chunk + TILE);
    acc += comp(bufL[0], bufT[0], chunk, h0);
    __syncthreads();                                  // tile1 ready, buf0 free

    stage(0, chunk + 2u * TILE);
    h0 = halo(chunk + 2u * TILE);
    acc += comp(bufL[1], bufT[1], chunk + TILE, h1);
    __syncthreads();                                  // tile2 ready, buf1 free

    stage(1, chunk + 3u * TILE);
    h1 = halo(chunk + 3u * TILE);
    acc += comp(bufL[0], bufT[0], chunk + 2u * TILE, h0);
    __syncthreads();                                  // tile3 ready

    acc += comp(bufL[1], bufT[1], chunk + 3u * TILE, h1);

    // 64-lane shuffle reduce -> 4-word LDS -> one atomic per block.
    #pragma unroll
    for (int off = 32; off > 0; off >>= 1)
        acc += __shfl_down(acc, off);

    if (ln == 0u) wsum[wv] = acc;
    __syncthreads();
    if (tid == 0u) {
        const float sblk = (wsum[0] + wsum[1] + wsum[2] + wsum[3]) * scale;
        atomicAdd(out, sblk);
    }
}

extern "C" void kernel_launch(void* const* d_in, const int* in_sizes, int n_in,
                              void* d_out, int out_size, void* d_ws, size_t ws_size,
                              hipStream_t stream)
{
    const float* logits  = (const float*)d_in[0];
    const float* targets = (const float*)d_in[1];
    float* out = (float*)d_out;

    const unsigned n = (unsigned)in_sizes[0];        // 25,000,000
    const float scale = 1.0f / (float)n;

    const unsigned per_block = NT * TILE;            // 8192 elements
    const unsigned nblocks = (n + per_block - 1u) / per_block;   // 3052

    // d_out is poisoned (0xAA) and never re-poisoned between replays:
    // zero it inside the captured sequence.
    hipMemsetAsync(out, 0, sizeof(float), stream);
    hbfl_kernel<<<nblocks, 256, 0, stream>>>(logits, targets, out, n, scale);
}

// Round 11
// 62.706 us; speedup vs baseline: 1.0083x; 1.0083x over previous
//
#include <hip/hip_runtime.h>

// 2-bit child->parent distance per column c (50-bit word): d = (DPACK >> 2c) & 3.
// d==0 -> not a child. Parent of column c is column c-d (d<=3, same row).
#define DPACK 0x00012493939124E4ULL

typedef float f32x4 __attribute__((ext_vector_type(4)));

struct B5 { f32x4 xa, xb, ta, tb, tp; };

__device__ __forceinline__ float parsel(unsigned d, float w1, float w2, float w3) {
    return (d == 1u) ? w1 : (d == 2u) ? w2 : w3;   // caller masks d==0
}

// MIR-level order pin (compile-time only; correctness never depends on it).
#define SB() __builtin_amdgcn_sched_barrier(0)

// VOLATILE loads: IR passes cannot sink/reorder them (this is what defeated
// R4/R5/R8/R9 -- loads sank to their uses BEFORE the MIR scheduler ran, so
// sched_barrier pinned nothing and regalloc collapsed the pipeline to
// depth-1). The compiler still owns s_waitcnt insertion, so counted waits
// stay correct even if it spills (unlike the R7/R8 asm-vmcnt failures).
__device__ __forceinline__ B5 loadb(const f32x4* l4p, const f32x4* t4p, unsigned p) {
    const unsigned q = 2u * p;
    const volatile f32x4* lv = (const volatile f32x4*)(l4p + q);
    const volatile f32x4* tv = (const volatile f32x4*)(t4p + q);
    const volatile f32x4* pv = (const volatile f32x4*)(t4p + (q - (unsigned)(q != 0u)));
    B5 v;
    v.xa = lv[0];
    v.xb = lv[1];
    v.ta = tv[0];
    v.tb = tv[1];
    v.tp = pv[0];        // prev 16B of targets; clamped @0 (never selected there)
    return v;
}

__device__ __forceinline__ float compb(const B5& v, unsigned dd) {
    // Targets window, flat elements 8p-4 .. 8p+7:  tp | ta | tb
    const float xs[8] = {v.xa[0],v.xa[1],v.xa[2],v.xa[3],
                         v.xb[0],v.xb[1],v.xb[2],v.xb[3]};
    const float ts[8] = {v.ta[0],v.ta[1],v.ta[2],v.ta[3],
                         v.tb[0],v.tb[1],v.tb[2],v.tb[3]};
    const float tpar[8] = {
        parsel((dd >> 0) & 3u,  v.tp[3], v.tp[2], v.tp[1]),
        parsel((dd >> 2) & 3u,  v.ta[0], v.tp[3], v.tp[2]),
        parsel((dd >> 4) & 3u,  v.ta[1], v.ta[0], v.tp[3]),
        parsel((dd >> 6) & 3u,  v.ta[2], v.ta[1], v.ta[0]),
        parsel((dd >> 8) & 3u,  v.ta[3], v.ta[2], v.ta[1]),
        parsel((dd >> 10) & 3u, v.tb[0], v.ta[3], v.ta[2]),
        parsel((dd >> 12) & 3u, v.tb[1], v.tb[0], v.ta[3]),
        parsel((dd >> 14) & 3u, v.tb[2], v.tb[1], v.tb[0])};
    float a = 0.0f;
    #pragma unroll
    for (int j = 0; j < 8; ++j) {
        const float x = xs[j], t = ts[j];
        // Binary targets (t in {0,1}): e = exp(-x*(2t-1));
        // bce = ln(1+e); pt = 1/(1+e); 1-pt = e*pt.   (R5-verified math)
        const float sgn = __builtin_fmaf(2.0f, t, -1.0f);
        const float e   = __expf(-x * sgn);
        const float den = 1.0f + e;
        const float pt  = __builtin_amdgcn_rcpf(den);
        const float bce = __logf(den);
        const float omp = e * pt;
        const float fo  = omp * omp * bce;               // focal / ALPHA
        float w = __builtin_fmaf(t, 0.375f, 0.1875f);    // ALPHA * class weight
        const unsigned dj = (dd >> (2 * j)) & 3u;
        const bool dbl = (dj != 0u) & (x > 0.5f) & (tpar[j] < 0.5f);
        w = dbl ? w + w : w;                             // (1 + penalty) factor
        a = __builtin_fmaf(fo, w, a);
    }
    return a;
}

// waves/EU=4 -> 128-VGPR cap; peak liveness ~110 (4 batches x 20 + misc).
__global__ __launch_bounds__(256, 4)
void hbfl_kernel(const float* __restrict__ logits,
                 const float* __restrict__ targets,
                 float* __restrict__ out,
                 unsigned n8, float scale)
{
    __shared__ float wsum[4];

    const unsigned tid = threadIdx.x;
    const unsigned g0  = blockIdx.x * 256u + tid;
    const unsigned str = gridDim.x * 256u;          // 524288 (2048 blocks)

    const f32x4* l4p = (const f32x4*)logits;
    const f32x4* t4p = (const f32x4*)targets;

    // 6 batch indices (clamped; masked at accumulate) + per-batch rotated
    // DPACK (bit pair j = d(column of element j of that batch)).
    unsigned pp[6], ddv[6]; bool vld[6];
    #pragma unroll
    for (int i = 0; i < 6; ++i) {
        const unsigned p = g0 + (unsigned)i * str;
        vld[i] = (p < n8);
        pp[i]  = vld[i] ? p : (n8 - 1u);
        const unsigned sh = 2u * ((8u * pp[i]) % 25u);
        ddv[i] = (unsigned)((DPACK >> sh) | (DPACK << (50u - sh)));
    }

    float acc = 0.0f;

    // Depth-3 pipeline (R8's schedule, now volatile-pinned):
    //   L0 L1 L2 | L3 | C0 | L4 | C1 | L5 | C2 | C3 C4 C5
    // 15 dwordx4 (240 B/lane = 15 KB/wave) in flight through each compute
    // phase; the compiler derives counted vmcnt before each Ci itself.
    B5 b0 = loadb(l4p, t4p, pp[0]);
    B5 b1 = loadb(l4p, t4p, pp[1]);
    B5 b2 = loadb(l4p, t4p, pp[2]);
    SB();
    B5 b3 = loadb(l4p, t4p, pp[3]);
    SB();
    acc += vld[0] ? compb(b0, ddv[0]) : 0.0f;
    SB();
    B5 b4 = loadb(l4p, t4p, pp[4]);
    SB();
    acc += vld[1] ? compb(b1, ddv[1]) : 0.0f;
    SB();
    B5 b5 = loadb(l4p, t4p, pp[5]);
    SB();
    acc += vld[2] ? compb(b2, ddv[2]) : 0.0f;
    SB();
    acc += vld[3] ? compb(b3, ddv[3]) : 0.0f;
    acc += vld[4] ? compb(b4, ddv[4]) : 0.0f;
    acc += vld[5] ? compb(b5, ddv[5]) : 0.0f;

    // 64-lane shuffle reduce -> 4-word LDS -> one atomic per block.
    #pragma unroll
    for (int off = 32; off > 0; off >>= 1)
        acc += __shfl_down(acc, off);

    const int wid = tid >> 6;
    if ((tid & 63u) == 0u) wsum[wid] = acc;
    __syncthreads();
    if (tid == 0u) {
        const float sblk = (wsum[0] + wsum[1] + wsum[2] + wsum[3]) * scale;
        atomicAdd(out, sblk);
    }
}

extern "C" void kernel_launch(void* const* d_in, const int* in_sizes, int n_in,
                              void* d_out, int out_size, void* d_ws, size_t ws_size,
                              hipStream_t stream)
{
    const float* logits  = (const float*)d_in[0];
    const float* targets = (const float*)d_in[1];
    float* out = (float*)d_out;

    const unsigned n  = (unsigned)in_sizes[0];   // 25,000,000 (divisible by 8)
    const unsigned n8 = n / 8u;                  // 3,125,000 float4-pairs
    const float scale = 1.0f / (float)n;

    // 2048 blocks = exactly one full co-residency wave (8 blocks/CU,
    // 32 waves/CU); 6 batches per thread (6*524288 >= n8), tails masked.
    const unsigned nblocks = 2048u;

    // d_out is poisoned (0xAA) and never re-poisoned between replays:
    // zero it inside the captured sequence.
    hipMemsetAsync(out, 0, sizeof(float), stream);
    hbfl_kernel<<<nblocks, 256, 0, stream>>>(logits, targets, out, n8, scale);
}

// Round 12
// 40.757 us; speedup vs baseline: 1.5513x; 1.5385x over previous
//
#include <hip/hip_runtime.h>

// 2-bit child->parent distance per column c (50-bit word): d = (DPACK >> 2c) & 3.
// d==0 -> not a child. Parent of column c is column c-d (d<=3, same row).
#define DPACK 0x00012493939124E4ULL

struct P5 { float4 xa, xb, ta, tb, tp; };

__device__ __forceinline__ float parsel(unsigned d, float w1, float w2, float w3) {
    return (d == 1u) ? w1 : (d == 2u) ? w2 : w3;   // caller masks d==0
}

__global__ __launch_bounds__(256)
void hbfl_kernel(const float* __restrict__ logits,
                 const float* __restrict__ targets,
                 float* __restrict__ partials,
                 unsigned n8, unsigned niter)
{
    __shared__ float wsum[4];

    const unsigned tid = threadIdx.x;
    const unsigned g0 = blockIdx.x * 256u + tid;      // pair-of-float4 index
    const unsigned stride = gridDim.x * 256u;         // 2050*256: 8*stride % 25 == 0

    // Loop-invariant per-thread column phase (8 consecutive elements).
    const unsigned c0 = (8u * g0) % 25u;
    unsigned d[8];
    #pragma unroll
    for (int j = 0; j < 8; ++j) {
        unsigned c = c0 + (unsigned)j;
        c = (c >= 25u) ? c - 25u : c;
        d[j] = (unsigned)(DPACK >> (2u * c)) & 3u;    // constant-index access only
    }

    const float4* l4p = reinterpret_cast<const float4*>(logits);
    const float4* t4p = reinterpret_cast<const float4*>(targets);

    auto LOAD = [&](unsigned p, P5& v) {
        const unsigned q = 2u * p;
        v.xa = l4p[q];
        v.xb = l4p[q + 1u];
        v.ta = t4p[q];
        v.tb = t4p[q + 1u];
        v.tp = t4p[q - (unsigned)(q != 0u)];          // prev 16B (L1/L2-hit; clamped @0)
    };

    float acc = 0.0f;

    auto COMP = [&](const P5& v, bool valid) {
        // Window of targets, flat elements 8p-4 .. 8p+7:
        //  W: tp.x tp.y tp.z tp.w | ta.x ta.y ta.z ta.w | tb.x tb.y tb.z tb.w
        const float xs[8] = {v.xa.x, v.xa.y, v.xa.z, v.xa.w,
                             v.xb.x, v.xb.y, v.xb.z, v.xb.w};
        const float ts[8] = {v.ta.x, v.ta.y, v.ta.z, v.ta.w,
                             v.tb.x, v.tb.y, v.tb.z, v.tb.w};
        const float tpar[8] = {
            parsel(d[0], v.tp.w, v.tp.z, v.tp.y),
            parsel(d[1], v.ta.x, v.tp.w, v.tp.z),
            parsel(d[2], v.ta.y, v.ta.x, v.tp.w),
            parsel(d[3], v.ta.z, v.ta.y, v.ta.x),
            parsel(d[4], v.ta.w, v.ta.z, v.ta.y),
            parsel(d[5], v.tb.x, v.ta.w, v.ta.z),
            parsel(d[6], v.tb.y, v.tb.x, v.ta.w),
            parsel(d[7], v.tb.z, v.tb.y, v.tb.x)};
        float a = 0.0f;
        #pragma unroll
        for (int j = 0; j < 8; ++j) {
            const float x = xs[j], t = ts[j];
            // Binary targets (t in {0,1}): e = exp(-x*(2t-1));
            // bce = ln(1+e); pt = 1/(1+e); 1-pt = e*pt.   (R5-verified math)
            const float sgn = __builtin_fmaf(2.0f, t, -1.0f);
            const float e   = __expf(-x * sgn);
            const float den = 1.0f + e;
            const float pt  = __builtin_amdgcn_rcpf(den);
            const float bce = __logf(den);
            const float omp = e * pt;                  // 1 - pt
            const float fo  = omp * omp * bce;         // focal / ALPHA
            float w = __builtin_fmaf(t, 0.375f, 0.1875f); // ALPHA * class weight
            const bool dbl = (d[j] != 0u) & (x > 0.5f) & (tpar[j] < 0.5f);
            w = dbl ? w + w : w;                       // (1 + penalty) factor
            a = __builtin_fmaf(fo, w, a);
        }
        acc += valid ? a : 0.0f;
    };

    // R5's two-stage pipeline (best measured real work).
    unsigned p = g0;
    P5 cur, nxt;
    LOAD(p, cur);                                     // g0 < n8 always
    for (unsigned it = 1u; it < niter; ++it) {
        const unsigned pn = p + stride;
        LOAD((pn < n8) ? pn : (n8 - 1u), nxt);        // clamped (masked later)
        COMP(cur, true);                              // p < n8 guaranteed here
        cur = nxt;
        p = pn;
    }
    COMP(cur, p < n8);                                // tail mask

    // 64-lane shuffle reduce -> 4-word LDS -> ONE PLAIN STORE per block.
    // (Same-address atomicAdd across all blocks was the serial tail that
    //  dominated R1-R11: ~12 ns x nblocks, data-path independent.)
    #pragma unroll
    for (int off = 32; off > 0; off >>= 1)
        acc += __shfl_down(acc, off);

    const int wid = tid >> 6;
    if ((tid & 63u) == 0u) wsum[wid] = acc;
    __syncthreads();
    if (tid == 0u)
        partials[blockIdx.x] = wsum[0] + wsum[1] + wsum[2] + wsum[3];
}

__global__ __launch_bounds__(256)
void reduce_kernel(const float* __restrict__ partials,
                   float* __restrict__ out,
                   unsigned nparts, float scale)
{
    __shared__ float wsum[4];
    const unsigned tid = threadIdx.x;
    float a = 0.0f;
    for (unsigned i = tid; i < nparts; i += 256u) a += partials[i];
    #pragma unroll
    for (int off = 32; off > 0; off >>= 1)
        a += __shfl_down(a, off);
    const int wid = tid >> 6;
    if ((tid & 63u) == 0u) wsum[wid] = a;
    __syncthreads();
    if (tid == 0u)
        out[0] = (wsum[0] + wsum[1] + wsum[2] + wsum[3]) * scale;
}

extern "C" void kernel_launch(void* const* d_in, const int* in_sizes, int n_in,
                              void* d_out, int out_size, void* d_ws, size_t ws_size,
                              hipStream_t stream)
{
    const float* logits  = (const float*)d_in[0];
    const float* targets = (const float*)d_in[1];
    float* out = (float*)d_out;
    float* ws  = (float*)d_ws;                   // 2050 floats of scratch

    const unsigned n  = (unsigned)in_sizes[0];   // 25,000,000 (divisible by 8)
    const unsigned n8 = n / 8u;                  // 3,125,000 float4-pairs
    const float scale = 1.0f / (float)n;

    // 2050 = 25*82: element stride (gridDim*256*8) ≡ 0 mod 25 -> per-thread
    // column phase loop-invariant; 6 batches per thread, tail masked.
    const unsigned nblocks = 2050u;
    const unsigned stride  = nblocks * 256u;
    const unsigned niter   = (n8 + stride - 1u) / stride;   // = 6

    // Stage 1 writes every ws[0..2049] each call; stage 2 reads them and
    // overwrites out[0] (covers the 0xAA poison) -- no memset needed,
    // deterministic across replays.
    hbfl_kernel<<<nblocks, 256, 0, stream>>>(logits, targets, ws, n8, niter);
    reduce_kernel<<<1, 256, 0, stream>>>(ws, out, nblocks, scale);
}